// Round 1
// 93.670 us; speedup vs baseline: 1.1332x; 1.1332x over previous
//
#include <hip/hip_runtime.h>
#include <math.h>
#include <float.h>

#define B_SZ 512
#define C_SZ 1000
#define D_SZ 512
#define K_TOP 10
#define K2 1024                       // [x^2 | x] vs [rd | -2*rd*p]
#define NSPLIT 4
#define KSPLIT (K2 / NSPLIT)          // 256
#define BC (B_SZ * C_SZ)

// ws layout:
//   halves: Whi [C][K2] then Wlo [C][K2]  (2 * 1,024,000 halves = 1,024,000 floats)
//   floats: t3 [1024], part [NSPLIT][B][C]
#define WHI_OFF 0                     // in halves
#define WLO_OFF (C_SZ * K2)           // in halves
#define T3_OFF  (C_SZ * K2)           // in floats (== bytes of both half planes / 4)
#define PART_OFF (T3_OFF + 1024)

using f16x8 = __attribute__((ext_vector_type(8))) _Float16;
using f32x4 = __attribute__((ext_vector_type(4))) float;

__device__ __forceinline__ void split2(float v, _Float16& h, _Float16& l) {
    h = (_Float16)v;
    l = (_Float16)(v - (float)h);
}

// ---------------------------------------------------------------------------
// Prep: one wave per class row (4 classes/block, 250 blocks).
// rd = softmax(min-trick). Emits W directly as f16 hi/lo planes:
//   Whi/Wlo[c, 0:512]   = split(rd)
//   Whi/Wlo[c, 512:1024]= split(-2*rd*p)
// t3[c] = sum rd*p^2 (fp32, exact path unchanged).
// ---------------------------------------------------------------------------
__global__ __launch_bounds__(256) void prep_kernel(const float* __restrict__ protos,
                                                   const float* __restrict__ ex2,
                                                   const float* __restrict__ ex1,
                                                   const int* __restrict__ cls_num,
                                                   float* __restrict__ ws) {
    _Float16* Whi = (_Float16*)ws + WHI_OFF;
    _Float16* Wlo = (_Float16*)ws + WLO_OFF;
    float* t3 = ws + T3_OFF;
    const int wid  = threadIdx.x >> 6;
    const int lane = threadIdx.x & 63;
    const int c = blockIdx.x * 4 + wid;

    const size_t rb = (size_t)c * D_SZ + lane * 8;
    float e2v[8], e1v[8], pv[8];
    *(float4*)&e2v[0] = *(const float4*)(ex2 + rb);
    *(float4*)&e2v[4] = *(const float4*)(ex2 + rb + 4);
    *(float4*)&e1v[0] = *(const float4*)(ex1 + rb);
    *(float4*)&e1v[4] = *(const float4*)(ex1 + rb + 4);
    *(float4*)&pv[0]  = *(const float4*)(protos + rb);
    *(float4*)&pv[4]  = *(const float4*)(protos + rb + 4);
    const float N = (float)cls_num[c];

    float v[8], mn = FLT_MAX;
    #pragma unroll
    for (int k = 0; k < 8; k++) {
        v[k] = sqrtf(N * e2v[k] * e2v[k] - e1v[k] * e1v[k]);
        mn = fminf(mn, v[k]);
    }
    #pragma unroll
    for (int off = 1; off < 64; off <<= 1) mn = fminf(mn, __shfl_xor(mn, off));

    float ev[8], s = 0.f;
    #pragma unroll
    for (int k = 0; k < 8; k++) { ev[k] = expf(mn - v[k]); s += ev[k]; }
    #pragma unroll
    for (int off = 1; off < 64; off <<= 1) s += __shfl_xor(s, off);
    const float inv = 1.0f / s;

    f16x8 h1, l1, h2, l2;
    float t = 0.f;
    #pragma unroll
    for (int k = 0; k < 8; k++) {
        const float rdv = ev[k] * inv;
        const float w2  = -2.0f * rdv * pv[k];
        _Float16 hh, ll;
        split2(rdv, hh, ll); h1[k] = hh; l1[k] = ll;
        split2(w2,  hh, ll); h2[k] = hh; l2[k] = ll;
        t = fmaf(rdv * pv[k], pv[k], t);
    }
    _Float16* wh = Whi + (size_t)c * K2 + lane * 8;
    _Float16* wl = Wlo + (size_t)c * K2 + lane * 8;
    *(f16x8*)(wh)         = h1;
    *(f16x8*)(wh + D_SZ)  = h2;
    *(f16x8*)(wl)         = l1;
    *(f16x8*)(wl + D_SZ)  = l2;

    #pragma unroll
    for (int off = 1; off < 64; off <<= 1) t += __shfl_xor(t, off);
    if (lane == 0) t3[c] = t;
}

// ---------------------------------------------------------------------------
// GEMM via f16x2 split-precision MFMA (fp32-equivalent: 4 cross products,
// ~2^-23 rel err). part[z][b][c] = sum_{k in z-chunk} A[b,k]*W[c,k].
// A virtual: x^2 (k<512) | x; split to hi/lo during LDS staging.
// Tile 64x64, BK=32 (= one 16x16x32 MFMA K-step), 4 waves (2x2 of 32x32).
// Grid 16 x 8 x 4 = 512 blocks -> 2 blocks/CU, 8 waves/CU.
// LDS stride 40 f16 (80 B): b128 frag reads 16B-aligned, 2-way bank alias only.
// ---------------------------------------------------------------------------
#define BM 64
#define BN 64
#define BK 32
#define LDT 40

__global__ __launch_bounds__(256, 2) void gemm_kernel(const float* __restrict__ x,
                                                      const _Float16* __restrict__ Whi,
                                                      const _Float16* __restrict__ Wlo,
                                                      float* __restrict__ part) {
    __shared__ __align__(16) _Float16 Ah[BM][LDT];
    __shared__ __align__(16) _Float16 Al[BM][LDT];
    __shared__ __align__(16) _Float16 Bh[BN][LDT];
    __shared__ __align__(16) _Float16 Bl[BN][LDT];

    const int tid  = threadIdx.x;
    const int lane = tid & 63;
    const int w    = tid >> 6;
    const int c0 = blockIdx.x * BN;
    const int b0 = blockIdx.y * BM;
    const int kz = blockIdx.z;
    const bool sq = (kz < NSPLIT / 2);
    const int khalf0 = sq ? kz * KSPLIT : kz * KSPLIT - D_SZ;

    const int srow = tid >> 2;            // 0..63 staging row
    const int sseg = (tid & 3) * 8;       // 0,8,16,24 (k offset)
    const int mw = (w >> 1) * 32;         // wave tile origin in b
    const int nw = (w & 1) * 32;          // wave tile origin in c
    const int lr = lane & 15;
    const int kg = lane >> 4;

    f32x4 acc[2][2];
    #pragma unroll
    for (int i = 0; i < 2; i++)
        #pragma unroll
        for (int j = 0; j < 2; j++)
            #pragma unroll
            for (int r = 0; r < 4; r++) acc[i][j][r] = 0.f;

    const int cW = c0 + srow;

    for (int ch = 0; ch < KSPLIT / BK; ch++) {
        const int kx = khalf0 + ch * BK + sseg;       // into x row
        const int kw = kz * KSPLIT + ch * BK + sseg;  // into W row

        float4 a0 = *(const float4*)(x + (size_t)(b0 + srow) * D_SZ + kx);
        float4 a1 = *(const float4*)(x + (size_t)(b0 + srow) * D_SZ + kx + 4);
        if (sq) {
            a0.x *= a0.x; a0.y *= a0.y; a0.z *= a0.z; a0.w *= a0.w;
            a1.x *= a1.x; a1.y *= a1.y; a1.z *= a1.z; a1.w *= a1.w;
        }
        const float av[8] = {a0.x, a0.y, a0.z, a0.w, a1.x, a1.y, a1.z, a1.w};
        f16x8 ah, al;
        #pragma unroll
        for (int j = 0; j < 8; j++) {
            _Float16 hh, ll;
            split2(av[j], hh, ll);
            ah[j] = hh; al[j] = ll;
        }

        f16x8 wh, wl;
        if (cW < C_SZ) {
            wh = *(const f16x8*)(Whi + (size_t)cW * K2 + kw);
            wl = *(const f16x8*)(Wlo + (size_t)cW * K2 + kw);
        } else {
            #pragma unroll
            for (int j = 0; j < 8; j++) { wh[j] = (_Float16)0.f; wl[j] = (_Float16)0.f; }
        }

        __syncthreads();   // previous iteration's frag reads done
        *(f16x8*)&Ah[srow][sseg] = ah;
        *(f16x8*)&Al[srow][sseg] = al;
        *(f16x8*)&Bh[srow][sseg] = wh;
        *(f16x8*)&Bl[srow][sseg] = wl;
        __syncthreads();   // tiles visible

        f16x8 fah[2], fal[2], fbh[2], fbl[2];
        #pragma unroll
        for (int i = 0; i < 2; i++) {
            fah[i] = *(const f16x8*)&Ah[mw + i * 16 + lr][kg * 8];
            fal[i] = *(const f16x8*)&Al[mw + i * 16 + lr][kg * 8];
            fbh[i] = *(const f16x8*)&Bh[nw + i * 16 + lr][kg * 8];
            fbl[i] = *(const f16x8*)&Bl[nw + i * 16 + lr][kg * 8];
        }
        #pragma unroll
        for (int i = 0; i < 2; i++)
            #pragma unroll
            for (int j = 0; j < 2; j++) {
                acc[i][j] = __builtin_amdgcn_mfma_f32_16x16x32_f16(fal[i], fbl[j], acc[i][j], 0, 0, 0);
                acc[i][j] = __builtin_amdgcn_mfma_f32_16x16x32_f16(fah[i], fbl[j], acc[i][j], 0, 0, 0);
                acc[i][j] = __builtin_amdgcn_mfma_f32_16x16x32_f16(fal[i], fbh[j], acc[i][j], 0, 0, 0);
                acc[i][j] = __builtin_amdgcn_mfma_f32_16x16x32_f16(fah[i], fbh[j], acc[i][j], 0, 0, 0);
            }
    }

    // C/D layout (verified m89/m91): col = lane&15, row = (lane>>4)*4 + reg
    float* o = part + (size_t)kz * BC;
    #pragma unroll
    for (int i = 0; i < 2; i++) {
        #pragma unroll
        for (int j = 0; j < 2; j++) {
            const int c = c0 + nw + j * 16 + lr;
            if (c < C_SZ) {
                #pragma unroll
                for (int r = 0; r < 4; r++) {
                    const int b = b0 + mw + i * 16 + kg * 4 + r;
                    o[(size_t)b * C_SZ + c] = acc[i][j][r];
                }
            }
        }
    }
}

// ---------------------------------------------------------------------------
// Top-K: per row, sum the 4 split-K partials + t3, then 10x butterfly min
// with index tie-break (lower index wins == lax.top_k stability).
// out[0..B): predict (float-encoded int), out[B..): topk_conf [B][K]
// ---------------------------------------------------------------------------
__global__ __launch_bounds__(256) void topk_kernel(const float* __restrict__ ws,
                                                   const int* __restrict__ proto_label,
                                                   float* __restrict__ out) {
    const float* part = ws + PART_OFF;
    const float* t3   = ws + T3_OFF;
    const int wid = threadIdx.x >> 6;
    const int lane = threadIdx.x & 63;
    const int b = blockIdx.x * 4 + wid;

    float vals[16];
    #pragma unroll
    for (int j = 0; j < 16; j++) {
        const int c = lane + j * 64;
        if (c < C_SZ) {
            const size_t idx = (size_t)b * C_SZ + c;
            float s = t3[c];
            #pragma unroll
            for (int z = 0; z < NSPLIT; z++)
                s += part[(size_t)z * BC + idx];
            vals[j] = s;
        } else {
            vals[j] = FLT_MAX;
        }
    }

    float kv[K_TOP];
    int ki[K_TOP];
    for (int t = 0; t < K_TOP; t++) {
        float bv = FLT_MAX;
        int bi = 0x7fffffff;
        #pragma unroll
        for (int j = 0; j < 16; j++) {
            const int c = lane + j * 64;
            if (vals[j] < bv) { bv = vals[j]; bi = c; }
        }
        #pragma unroll
        for (int off = 1; off < 64; off <<= 1) {
            const float ov = __shfl_xor(bv, off);
            const int oi = __shfl_xor(bi, off);
            if (ov < bv || (ov == bv && oi < bi)) { bv = ov; bi = oi; }
        }
        kv[t] = bv;
        ki[t] = bi;
        if ((bi & 63) == lane) vals[bi >> 6] = FLT_MAX;
    }

    if (lane == 0) {
        float S = 0.f;
        #pragma unroll
        for (int t = 0; t < K_TOP; t++) S += kv[t];
        float conf[K_TOP];
        #pragma unroll
        for (int t = 0; t < K_TOP; t++) {
            conf[t] = S / kv[t];
            out[B_SZ + b * K_TOP + t] = conf[t];
        }
        int best = 0;
        for (int t = 1; t < K_TOP; t++)
            if (conf[t] > conf[best]) best = t;
        out[b] = (float)proto_label[ki[best]];
    }
}

extern "C" void kernel_launch(void* const* d_in, const int* in_sizes, int n_in,
                              void* d_out, int out_size, void* d_ws, size_t ws_size,
                              hipStream_t stream) {
    const float* x           = (const float*)d_in[0];
    const float* protos      = (const float*)d_in[1];
    const float* ex2         = (const float*)d_in[2];
    const float* ex1         = (const float*)d_in[3];
    const int*   cls_num     = (const int*)d_in[4];
    const int*   proto_label = (const int*)d_in[5];

    float* ws  = (float*)d_ws;
    float* out = (float*)d_out;

    prep_kernel<<<C_SZ / 4, 256, 0, stream>>>(protos, ex2, ex1, cls_num, ws);

    dim3 g2((C_SZ + BN - 1) / BN, B_SZ / BM, NSPLIT);   // 16 x 8 x 4 = 512
    gemm_kernel<<<g2, 256, 0, stream>>>(x,
                                        (const _Float16*)ws + WHI_OFF,
                                        (const _Float16*)ws + WLO_OFF,
                                        ws + PART_OFF);

    topk_kernel<<<B_SZ / 4, 256, 0, stream>>>(ws, proto_label, out);
}